// Round 8
// baseline (113.112 us; speedup 1.0000x reference)
//
#include <hip/hip_runtime.h>
#include <hip/hip_bf16.h>

// Problem constants (fixed by the reference):
constexpr int NB = 256;   // batch
constexpr int SQ = 512;   // sequence length
constexpr int ED = 512;   // encoder dim
constexpr int DD = 512;   // decoder dim
constexpr int UU = 64;    // attention units
constexpr int NT = 4;     // s-tiles per batch
constexpr int TS = 128;   // rows per tile

typedef __attribute__((ext_vector_type(8))) short bf16x8;
typedef __attribute__((ext_vector_type(4))) float f32x4;
typedef __attribute__((ext_vector_type(4))) unsigned int u32x4;

__device__ __forceinline__ unsigned short bf16_rne(float f) {
  unsigned int u = __float_as_uint(f);
  u += 0x7FFFu + ((u >> 16) & 1u);
  return (unsigned short)(u >> 16);
}

// Truncate-truncate pair split: v ~= hi + lo to ~2^-16 rel.
__device__ __forceinline__ uint2 split2(float v0, float v1) {
  unsigned int u0 = __float_as_uint(v0), u1 = __float_as_uint(v1);
  unsigned int h0 = u0 & 0xFFFF0000u, h1 = u1 & 0xFFFF0000u;
  unsigned int hi = (u0 >> 16) | h1;
  float r0 = v0 - __uint_as_float(h0);
  float r1 = v1 - __uint_as_float(h1);
  unsigned int lo = (__float_as_uint(r0) >> 16) | (__float_as_uint(r1) & 0xFFFF0000u);
  return make_uint2(hi, lo);
}

// ws layout (bytes):
constexpr size_t WS_DEC   = 131072;
constexpr size_t WS_MBUF  = 196608;
constexpr size_t WS_LBUF  = 200704;
constexpr size_t WS_CTILE = 204800;

// ---------------------------------------------------------------------------
// Kernel P1: split w2 into hi/lo bf16 MFMA B-fragments; per k-step 8192 B.
// Layout (ushort): off = ks*4096 + hl*2048 + nt*512 + lane*8 + j
// ---------------------------------------------------------------------------
__global__ void prep_w2_frags(const float* __restrict__ w2,
                              unsigned short* __restrict__ wsb) {
  int tid = blockIdx.x * 256 + threadIdx.x;   // 0..65535
  int j    = tid & 7;
  int lane = (tid >> 3) & 63;
  int nt   = (tid >> 9) & 3;
  int hl   = (tid >> 11) & 1;
  int ks   = tid >> 12;
  int e = ks * 32 + (lane >> 4) * 8 + j;
  int u = nt * 16 + (lane & 15);
  float v = w2[e * UU + u];
  unsigned short hi = bf16_rne(v);
  unsigned short o;
  if (hl == 0) {
    o = hi;
  } else {
    float hif = __uint_as_float((unsigned int)hi << 16);
    o = bf16_rne(v - hif);
  }
  wsb[tid] = o;
}

// ---------------------------------------------------------------------------
// Kernel P2: dec[b,u] = dh[b,:]·w1[:,u] + w1b[u] + w2b[u]
// ---------------------------------------------------------------------------
__global__ __launch_bounds__(256) void dec_proj(
    const float* __restrict__ dh, const float* __restrict__ w1,
    const float* __restrict__ w1b, const float* __restrict__ w2b,
    float* __restrict__ dec_ws) {
  const int b = blockIdx.x;
  const int t = threadIdx.x;
  const int wave = t >> 6;
  const int lane = t & 63;
  __shared__ float red[256];
  const float* dhb = dh + (size_t)b * DD;
  const int e0 = wave * 128;
  float s = 0.f;
  #pragma unroll 8
  for (int i = 0; i < 128; ++i) {
    int e = e0 + i;
    s = fmaf(dhb[e], w1[e * UU + lane], s);
  }
  red[t] = s;
  __syncthreads();
  if (t < 64) {
    float d = w1b[t] + w2b[t] + red[t] + red[64 + t] + red[128 + t] + red[192 + t];
    dec_ws[b * UU + t] = d;
  }
}

// ---------------------------------------------------------------------------
// Kernel A: per (b, 128-row tile), 512 threads = 8 waves (wave = 16 rows).
// ZERO-BARRIER k-loop: the full B fragment set (128 KB hi+lo) is preloaded
// into LDS once (single __syncthreads for the whole kernel); A goes straight
// to registers with a 2-deep rotating prefetch. Round-7's counted-vmcnt ring
// proved memory-system-invariant pacing (L3-warm == HBM-cold at 157 us):
// the 32 barrier/waitcnt pairs per block were the wall, not memory.
// Cost: 137 KB LDS -> 1 block/CU (8 waves, 25% occ) — pure-stream ILP.
// ---------------------------------------------------------------------------
__global__ __launch_bounds__(512, 2) void attn_tile(
    const float* __restrict__ x,
    const float* __restrict__ vk,
    const unsigned short* __restrict__ wsb,
    const float* __restrict__ dec_ws,
    float* __restrict__ mbuf, float* __restrict__ lbuf,
    float* __restrict__ ctile,
    float* __restrict__ out)
{
  const int b    = blockIdx.x >> 2;
  const int tile = blockIdx.x & 3;
  const int t = threadIdx.x;
  const int wave = t >> 6;
  const int lane = t & 63;

  __shared__ __align__(16) unsigned short blds[65536];  // 128 KB: all B frags
  __shared__ float score_lds[TS];
  __shared__ float p_lds[TS];
  __shared__ float dec_lds[64];
  __shared__ float v_lds[64];
  __shared__ __align__(16) float cpart[4][512];         // 8 KB

  // ---- one-time preloads ---------------------------------------------------
  // B: thread t copies ushorts [t*128, t*128+128) = 256 B (16 x dwordx4).
  {
    const bf16x8* src = (const bf16x8*)(wsb + t * 128);
    bf16x8* dst = (bf16x8*)&blds[t * 128];
    #pragma unroll
    for (int i = 0; i < 16; ++i) dst[i] = src[i];
  }
  if (t < 64) {
    dec_lds[t] = dec_ws[b * UU + t];
    v_lds[t] = vk[t];
  }
  __syncthreads();   // the only barrier before the epilogue phases

  // ---- projection GEMM over this tile's 128 rows (no barriers) ------------
  const int row0 = tile * TS + wave * 16;
  const float* aptr =
      x + ((size_t)b * SQ + row0 + (lane & 15)) * ED + ((lane >> 4) * 8);

  const f32x4 zero4 = {0.f, 0.f, 0.f, 0.f};
  f32x4 acc[4];
  #pragma unroll
  for (int n = 0; n < 4; ++n) acc[n] = zero4;

  // manual 2-deep rotating A prefetch (k and k+1 in flight)
  float4 pa0[2], pa1[2];
  pa0[0] = *(const float4*)(aptr);
  pa1[0] = *(const float4*)(aptr + 4);
  pa0[1] = *(const float4*)(aptr + 32);
  pa1[1] = *(const float4*)(aptr + 36);

  #pragma unroll
  for (int k = 0; k < 16; ++k) {
    float4 a0 = pa0[k & 1], a1 = pa1[k & 1];
    if (k < 14) {
      pa0[k & 1] = *(const float4*)(aptr + (k + 2) * 32);
      pa1[k & 1] = *(const float4*)(aptr + (k + 2) * 32 + 4);
    }
    bf16x8 bhi[4], blo[4];
    #pragma unroll
    for (int n = 0; n < 4; ++n) {
      bhi[n] = *(const bf16x8*)&blds[k * 4096 + n * 512 + lane * 8];
      blo[n] = *(const bf16x8*)&blds[k * 4096 + 2048 + n * 512 + lane * 8];
    }
    uint2 p0 = split2(a0.x, a0.y);
    uint2 p1 = split2(a0.z, a0.w);
    uint2 p2 = split2(a1.x, a1.y);
    uint2 p3 = split2(a1.z, a1.w);
    u32x4 hi, lo;
    hi[0] = p0.x; lo[0] = p0.y;
    hi[1] = p1.x; lo[1] = p1.y;
    hi[2] = p2.x; lo[2] = p2.y;
    hi[3] = p3.x; lo[3] = p3.y;
    bf16x8 ahi = __builtin_bit_cast(bf16x8, hi);
    bf16x8 alo = __builtin_bit_cast(bf16x8, lo);
    #pragma unroll
    for (int n = 0; n < 4; ++n) {
      acc[n] = __builtin_amdgcn_mfma_f32_16x16x32_bf16(ahi, bhi[n], acc[n], 0, 0, 0);
      acc[n] = __builtin_amdgcn_mfma_f32_16x16x32_bf16(ahi, blo[n], acc[n], 0, 0, 0);
      acc[n] = __builtin_amdgcn_mfma_f32_16x16x32_bf16(alo, bhi[n], acc[n], 0, 0, 0);
    }
  }

  // ---- scores: score[s] = sum_u tanh(enc + dec) * v ------------------------
  // C/D layout (m89/m91): col u = lane&15 (+16*n), row = (lane>>4)*4 + r
  {
    const int ul = lane & 15;
    const int rg = lane >> 4;
    #pragma unroll
    for (int r = 0; r < 4; ++r) {
      float partsc = 0.f;
      #pragma unroll
      for (int n = 0; n < 4; ++n) {
        int u = n * 16 + ul;
        float z = acc[n][r] + dec_lds[u];
        float ez = __expf(2.f * z);              // tanh via exp
        float th = 1.f - 2.f / (ez + 1.f);
        partsc = fmaf(th, v_lds[u], partsc);
      }
      partsc += __shfl_xor(partsc, 1);
      partsc += __shfl_xor(partsc, 2);
      partsc += __shfl_xor(partsc, 4);
      partsc += __shfl_xor(partsc, 8);
      if (ul == 0) score_lds[wave * 16 + rg * 4 + r] = partsc;
    }
  }
  __syncthreads();

  // ---- tile-local softmax pieces ------------------------------------------
  float mx = -1e30f;
  #pragma unroll
  for (int i = 0; i < TS; i += 4) {
    float4 s4 = *(const float4*)&score_lds[i];
    mx = fmaxf(mx, fmaxf(fmaxf(s4.x, s4.y), fmaxf(s4.z, s4.w)));
  }
  if (t < TS) {
    float p = __expf(score_lds[t] - mx);
    p_lds[t] = p;
    out[(size_t)NB * ED + (size_t)b * SQ + tile * TS + t] = p;  // unnormalized
  }
  __syncthreads();
  if (t < 64) {
    float v = p_lds[t] + p_lds[t + 64];
    v += __shfl_xor(v, 1);  v += __shfl_xor(v, 2);
    v += __shfl_xor(v, 4);  v += __shfl_xor(v, 8);
    v += __shfl_xor(v, 16); v += __shfl_xor(v, 32);
    if (t == 0) {
      mbuf[b * NT + tile] = mx;
      lbuf[b * NT + tile] = v;
    }
  }

  // ---- partial context: ctile[e] = sum_{s in tile} p[s] x[b,s,e] ----------
  // (direct float4 loads; tile is L2/L3-hot from the proj pass)
  {
    const int subset = t >> 7;          // 0..3
    const int ec = t & 127;             // float4 e-chunk
    const float* xc = x + ((size_t)b * SQ + tile * TS) * ED + ec * 4;
    f32x4 c = zero4;
    #pragma unroll 8
    for (int i = 0; i < 32; ++i) {
      int s = subset + i * 4;
      float4 v = *(const float4*)(xc + (size_t)s * ED);
      float p = p_lds[s];
      c[0] = fmaf(p, v.x, c[0]);
      c[1] = fmaf(p, v.y, c[1]);
      c[2] = fmaf(p, v.z, c[2]);
      c[3] = fmaf(p, v.w, c[3]);
    }
    *(f32x4*)&cpart[subset][ec * 4] = c;
  }
  __syncthreads();
  ctile[((size_t)b * NT + tile) * ED + t] =
      cpart[0][t] + cpart[1][t] + cpart[2][t] + cpart[3][t];
}

// ---------------------------------------------------------------------------
// Kernel B: combine tiles (flash algebra). att *= e^{m_t-M}/L; ctx = sum.
// ---------------------------------------------------------------------------
__global__ __launch_bounds__(256) void combine(
    const float* __restrict__ mbuf, const float* __restrict__ lbuf,
    const float* __restrict__ ctile, float* __restrict__ out) {
  const int b = blockIdx.x;
  const int t = threadIdx.x;
  float m0 = mbuf[b * NT + 0], m1 = mbuf[b * NT + 1];
  float m2 = mbuf[b * NT + 2], m3 = mbuf[b * NT + 3];
  float M = fmaxf(fmaxf(m0, m1), fmaxf(m2, m3));
  float e0 = __expf(m0 - M), e1 = __expf(m1 - M);
  float e2 = __expf(m2 - M), e3 = __expf(m3 - M);
  float L = lbuf[b * NT + 0] * e0 + lbuf[b * NT + 1] * e1 +
            lbuf[b * NT + 2] * e2 + lbuf[b * NT + 3] * e3;
  float inv = 1.f / L;
  float sc[NT] = {e0 * inv, e1 * inv, e2 * inv, e3 * inv};

  float* att = out + (size_t)NB * ED + (size_t)b * SQ;
  #pragma unroll
  for (int s = t; s < SQ; s += 256) att[s] *= sc[s >> 7];

  const float* ct = ctile + (size_t)b * NT * ED;
  #pragma unroll
  for (int e = t; e < ED; e += 256) {
    float c = ct[e] * sc[0] + ct[ED + e] * sc[1] +
              ct[2 * ED + e] * sc[2] + ct[3 * ED + e] * sc[3];
    out[(size_t)b * ED + e] = c;
  }
}

// ---------------------------------------------------------------------------
extern "C" void kernel_launch(void* const* d_in, const int* in_sizes, int n_in,
                              void* d_out, int out_size, void* d_ws, size_t ws_size,
                              hipStream_t stream) {
  const float* dh  = (const float*)d_in[0];
  const float* x   = (const float*)d_in[1];
  const float* w1  = (const float*)d_in[2];
  const float* w1b = (const float*)d_in[3];
  const float* w2  = (const float*)d_in[4];
  const float* w2b = (const float*)d_in[5];
  const float* vk  = (const float*)d_in[6];
  // d_in[7] = v_bias: softmax exactly invariant -> unused.
  unsigned short* wsb = (unsigned short*)d_ws;
  float* dec_ws = (float*)((char*)d_ws + WS_DEC);
  float* mbuf   = (float*)((char*)d_ws + WS_MBUF);
  float* lbuf   = (float*)((char*)d_ws + WS_LBUF);
  float* ctile  = (float*)((char*)d_ws + WS_CTILE);
  float* out = (float*)d_out;

  prep_w2_frags<<<256, 256, 0, stream>>>(w2, wsb);
  dec_proj<<<NB, 256, 0, stream>>>(dh, w1, w1b, w2b, dec_ws);
  attn_tile<<<NB * NT, 512, 0, stream>>>(x, vk, wsb, dec_ws, mbuf, lbuf, ctile, out);
  combine<<<NB, 256, 0, stream>>>(mbuf, lbuf, ctile, out);
}

// Round 9
// 102.008 us; speedup vs baseline: 1.1089x; 1.1089x over previous
//
#include <hip/hip_runtime.h>
#include <hip/hip_bf16.h>

// Problem constants (fixed by the reference):
constexpr int NB = 256;   // batch
constexpr int SQ = 512;   // sequence length
constexpr int ED = 512;   // encoder dim
constexpr int DD = 512;   // decoder dim
constexpr int UU = 64;    // attention units
constexpr int NT = 4;     // s-tiles per batch
constexpr int TS = 128;   // rows per tile

typedef __attribute__((ext_vector_type(8))) short bf16x8;
typedef __attribute__((ext_vector_type(4))) float f32x4;
typedef __attribute__((ext_vector_type(4))) unsigned int u32x4;

__device__ __forceinline__ unsigned short bf16_rne(float f) {
  unsigned int u = __float_as_uint(f);
  u += 0x7FFFu + ((u >> 16) & 1u);
  return (unsigned short)(u >> 16);
}

// Truncate-truncate pair split: v ~= hi + lo to ~2^-16 rel.
__device__ __forceinline__ uint2 split2(float v0, float v1) {
  unsigned int u0 = __float_as_uint(v0), u1 = __float_as_uint(v1);
  unsigned int h0 = u0 & 0xFFFF0000u, h1 = u1 & 0xFFFF0000u;
  unsigned int hi = (u0 >> 16) | h1;
  float r0 = v0 - __uint_as_float(h0);
  float r1 = v1 - __uint_as_float(h1);
  unsigned int lo = (__float_as_uint(r0) >> 16) | (__float_as_uint(r1) & 0xFFFF0000u);
  return make_uint2(hi, lo);
}

// ws layout (bytes):
constexpr size_t WS_DEC   = 131072;
constexpr size_t WS_MBUF  = 196608;
constexpr size_t WS_LBUF  = 200704;
constexpr size_t WS_CTILE = 204800;

// ---------------------------------------------------------------------------
// Kernel P1: w2 -> bf16-RNE (hi only) MFMA B-fragments. 64 KB total.
// Layout (ushort): off = ks*2048 + nt*512 + lane*8 + j
//   (B[k][col] for mfma_16x16x32: lane l holds k=(l>>4)*8+j, col=l&15)
// B-lo residual dropped deliberately: est. score err ~2e-3 rms, inside the
// 7.07e-3 threshold. Buys 64 KB of LDS -> 2 blocks/CU (round-8 post-mortem:
// per-wave-stall-bound at <=2 waves/SIMD was the invariant wall).
// ---------------------------------------------------------------------------
__global__ void prep_w2_frags(const float* __restrict__ w2,
                              unsigned short* __restrict__ wsb) {
  int tid = blockIdx.x * 256 + threadIdx.x;   // 0..32767
  int j    = tid & 7;
  int lane = (tid >> 3) & 63;
  int nt   = (tid >> 9) & 3;
  int ks   = tid >> 11;
  int e = ks * 32 + (lane >> 4) * 8 + j;
  int u = nt * 16 + (lane & 15);
  wsb[tid] = bf16_rne(w2[e * UU + u]);
}

// ---------------------------------------------------------------------------
// Kernel P2: dec[b,u] = dh[b,:]·w1[:,u] + w1b[u] + w2b[u]
// ---------------------------------------------------------------------------
__global__ __launch_bounds__(256) void dec_proj(
    const float* __restrict__ dh, const float* __restrict__ w1,
    const float* __restrict__ w1b, const float* __restrict__ w2b,
    float* __restrict__ dec_ws) {
  const int b = blockIdx.x;
  const int t = threadIdx.x;
  const int wave = t >> 6;
  const int lane = t & 63;
  __shared__ float red[256];
  const float* dhb = dh + (size_t)b * DD;
  const int e0 = wave * 128;
  float s = 0.f;
  #pragma unroll 8
  for (int i = 0; i < 128; ++i) {
    int e = e0 + i;
    s = fmaf(dhb[e], w1[e * UU + lane], s);
  }
  red[t] = s;
  __syncthreads();
  if (t < 64) {
    float d = w1b[t] + w2b[t] + red[t] + red[64 + t] + red[128 + t] + red[192 + t];
    dec_ws[b * UU + t] = d;
  }
}

// ---------------------------------------------------------------------------
// Kernel A: per (b, 128-row tile), 512 threads = 8 waves (wave = 16 rows).
// B-hi (64 KB) preloaded once, conflict-free (wave writes 1 KB contiguous);
// free-running barrier-less k-loop; A direct-to-register with 4-deep rotating
// prefetch; 2 MFMA per (k,n): (ahi + alo) x bhi — A exact, B bf16-RNE.
// LDS ~73 KB -> 2 blocks/CU -> 4 waves/SIMD: per-wave load stalls now have
// 3 other waves to hide under (rounds 1-8 had 2/SIMD and were stall-bound).
// ---------------------------------------------------------------------------
__global__ __launch_bounds__(512, 4) void attn_tile(
    const float* __restrict__ x,
    const float* __restrict__ vk,
    const unsigned short* __restrict__ wsb,
    const float* __restrict__ dec_ws,
    float* __restrict__ mbuf, float* __restrict__ lbuf,
    float* __restrict__ ctile,
    float* __restrict__ out)
{
  const int b    = blockIdx.x >> 2;
  const int tile = blockIdx.x & 3;
  const int t = threadIdx.x;
  const int wave = t >> 6;
  const int lane = t & 63;

  __shared__ __align__(16) unsigned short blds[32768];  // 64 KB: B-hi frags
  __shared__ float score_lds[TS];
  __shared__ float p_lds[TS];
  __shared__ float dec_lds[64];
  __shared__ float v_lds[64];
  __shared__ __align__(16) float cpart[4][512];         // 8 KB

  // ---- one-time preloads (conflict-free: wave writes contiguous 1 KB) ----
  #pragma unroll
  for (int i = 0; i < 8; ++i) {
    *(bf16x8*)&blds[i * 4096 + t * 8] = *(const bf16x8*)(wsb + i * 4096 + t * 8);
  }
  if (t < 64) {
    dec_lds[t] = dec_ws[b * UU + t];
    v_lds[t] = vk[t];
  }
  __syncthreads();   // the only barrier before the epilogue phases

  // ---- projection GEMM over this tile's 128 rows (no barriers) ------------
  const int row0 = tile * TS + wave * 16;
  const float* aptr =
      x + ((size_t)b * SQ + row0 + (lane & 15)) * ED + ((lane >> 4) * 8);

  const f32x4 zero4 = {0.f, 0.f, 0.f, 0.f};
  f32x4 acc[4];
  #pragma unroll
  for (int n = 0; n < 4; ++n) acc[n] = zero4;

  // manual 4-deep rotating A prefetch (k .. k+3 in flight)
  float4 pa0[4], pa1[4];
  #pragma unroll
  for (int q = 0; q < 4; ++q) {
    pa0[q] = *(const float4*)(aptr + q * 32);
    pa1[q] = *(const float4*)(aptr + q * 32 + 4);
  }

  #pragma unroll
  for (int k = 0; k < 16; ++k) {
    float4 a0 = pa0[k & 3], a1 = pa1[k & 3];
    if (k < 12) {
      pa0[k & 3] = *(const float4*)(aptr + (k + 4) * 32);
      pa1[k & 3] = *(const float4*)(aptr + (k + 4) * 32 + 4);
    }
    bf16x8 bhi[4];
    #pragma unroll
    for (int n = 0; n < 4; ++n) {
      bhi[n] = *(const bf16x8*)&blds[k * 2048 + n * 512 + lane * 8];
    }
    uint2 p0 = split2(a0.x, a0.y);
    uint2 p1 = split2(a0.z, a0.w);
    uint2 p2 = split2(a1.x, a1.y);
    uint2 p3 = split2(a1.z, a1.w);
    u32x4 hi, lo;
    hi[0] = p0.x; lo[0] = p0.y;
    hi[1] = p1.x; lo[1] = p1.y;
    hi[2] = p2.x; lo[2] = p2.y;
    hi[3] = p3.x; lo[3] = p3.y;
    bf16x8 ahi = __builtin_bit_cast(bf16x8, hi);
    bf16x8 alo = __builtin_bit_cast(bf16x8, lo);
    #pragma unroll
    for (int n = 0; n < 4; ++n) {
      acc[n] = __builtin_amdgcn_mfma_f32_16x16x32_bf16(ahi, bhi[n], acc[n], 0, 0, 0);
      acc[n] = __builtin_amdgcn_mfma_f32_16x16x32_bf16(alo, bhi[n], acc[n], 0, 0, 0);
    }
  }

  // ---- scores: score[s] = sum_u tanh(enc + dec) * v ------------------------
  // C/D layout (m89/m91): col u = lane&15 (+16*n), row = (lane>>4)*4 + r
  {
    const int ul = lane & 15;
    const int rg = lane >> 4;
    #pragma unroll
    for (int r = 0; r < 4; ++r) {
      float partsc = 0.f;
      #pragma unroll
      for (int n = 0; n < 4; ++n) {
        int u = n * 16 + ul;
        float z = acc[n][r] + dec_lds[u];
        float ez = __expf(2.f * z);              // tanh via exp
        float th = 1.f - 2.f / (ez + 1.f);
        partsc = fmaf(th, v_lds[u], partsc);
      }
      partsc += __shfl_xor(partsc, 1);
      partsc += __shfl_xor(partsc, 2);
      partsc += __shfl_xor(partsc, 4);
      partsc += __shfl_xor(partsc, 8);
      if (ul == 0) score_lds[wave * 16 + rg * 4 + r] = partsc;
    }
  }
  __syncthreads();

  // ---- tile-local softmax pieces ------------------------------------------
  float mx = -1e30f;
  #pragma unroll
  for (int i = 0; i < TS; i += 4) {
    float4 s4 = *(const float4*)&score_lds[i];
    mx = fmaxf(mx, fmaxf(fmaxf(s4.x, s4.y), fmaxf(s4.z, s4.w)));
  }
  if (t < TS) {
    float p = __expf(score_lds[t] - mx);
    p_lds[t] = p;
    out[(size_t)NB * ED + (size_t)b * SQ + tile * TS + t] = p;  // unnormalized
  }
  __syncthreads();
  if (t < 64) {
    float v = p_lds[t] + p_lds[t + 64];
    v += __shfl_xor(v, 1);  v += __shfl_xor(v, 2);
    v += __shfl_xor(v, 4);  v += __shfl_xor(v, 8);
    v += __shfl_xor(v, 16); v += __shfl_xor(v, 32);
    if (t == 0) {
      mbuf[b * NT + tile] = mx;
      lbuf[b * NT + tile] = v;
    }
  }

  // ---- partial context: ctile[e] = sum_{s in tile} p[s] x[b,s,e] ----------
  // (direct float4 loads; tile is L2/L3-hot from the proj pass)
  {
    const int subset = t >> 7;          // 0..3
    const int ec = t & 127;             // float4 e-chunk
    const float* xc = x + ((size_t)b * SQ + tile * TS) * ED + ec * 4;
    f32x4 c = zero4;
    #pragma unroll 8
    for (int i = 0; i < 32; ++i) {
      int s = subset + i * 4;
      float4 v = *(const float4*)(xc + (size_t)s * ED);
      float p = p_lds[s];
      c[0] = fmaf(p, v.x, c[0]);
      c[1] = fmaf(p, v.y, c[1]);
      c[2] = fmaf(p, v.z, c[2]);
      c[3] = fmaf(p, v.w, c[3]);
    }
    *(f32x4*)&cpart[subset][ec * 4] = c;
  }
  __syncthreads();
  ctile[((size_t)b * NT + tile) * ED + t] =
      cpart[0][t] + cpart[1][t] + cpart[2][t] + cpart[3][t];
}

// ---------------------------------------------------------------------------
// Kernel B: combine tiles (flash algebra). att *= e^{m_t-M}/L; ctx = sum.
// ---------------------------------------------------------------------------
__global__ __launch_bounds__(256) void combine(
    const float* __restrict__ mbuf, const float* __restrict__ lbuf,
    const float* __restrict__ ctile, float* __restrict__ out) {
  const int b = blockIdx.x;
  const int t = threadIdx.x;
  float m0 = mbuf[b * NT + 0], m1 = mbuf[b * NT + 1];
  float m2 = mbuf[b * NT + 2], m3 = mbuf[b * NT + 3];
  float M = fmaxf(fmaxf(m0, m1), fmaxf(m2, m3));
  float e0 = __expf(m0 - M), e1 = __expf(m1 - M);
  float e2 = __expf(m2 - M), e3 = __expf(m3 - M);
  float L = lbuf[b * NT + 0] * e0 + lbuf[b * NT + 1] * e1 +
            lbuf[b * NT + 2] * e2 + lbuf[b * NT + 3] * e3;
  float inv = 1.f / L;
  float sc[NT] = {e0 * inv, e1 * inv, e2 * inv, e3 * inv};

  float* att = out + (size_t)NB * ED + (size_t)b * SQ;
  #pragma unroll
  for (int s = t; s < SQ; s += 256) att[s] *= sc[s >> 7];

  const float* ct = ctile + (size_t)b * NT * ED;
  #pragma unroll
  for (int e = t; e < ED; e += 256) {
    float c = ct[e] * sc[0] + ct[ED + e] * sc[1] +
              ct[2 * ED + e] * sc[2] + ct[3 * ED + e] * sc[3];
    out[(size_t)b * ED + e] = c;
  }
}

// ---------------------------------------------------------------------------
extern "C" void kernel_launch(void* const* d_in, const int* in_sizes, int n_in,
                              void* d_out, int out_size, void* d_ws, size_t ws_size,
                              hipStream_t stream) {
  const float* dh  = (const float*)d_in[0];
  const float* x   = (const float*)d_in[1];
  const float* w1  = (const float*)d_in[2];
  const float* w1b = (const float*)d_in[3];
  const float* w2  = (const float*)d_in[4];
  const float* w2b = (const float*)d_in[5];
  const float* vk  = (const float*)d_in[6];
  // d_in[7] = v_bias: softmax exactly invariant -> unused.
  unsigned short* wsb = (unsigned short*)d_ws;
  float* dec_ws = (float*)((char*)d_ws + WS_DEC);
  float* mbuf   = (float*)((char*)d_ws + WS_MBUF);
  float* lbuf   = (float*)((char*)d_ws + WS_LBUF);
  float* ctile  = (float*)((char*)d_ws + WS_CTILE);
  float* out = (float*)d_out;

  prep_w2_frags<<<128, 256, 0, stream>>>(w2, wsb);
  dec_proj<<<NB, 256, 0, stream>>>(dh, w1, w1b, w2b, dec_ws);
  attn_tile<<<NB * NT, 512, 0, stream>>>(x, vk, wsb, dec_ws, mbuf, lbuf, ctile, out);
  combine<<<NB, 256, 0, stream>>>(mbuf, lbuf, ctile, out);
}